// Round 1
// baseline (320.295 us; speedup 1.0000x reference)
//
#include <hip/hip_runtime.h>
#include <math.h>

// Problem: S=1, B=32, H=4096, E=8. MoE top-2 routing + per-expert matvec.
// out[b][d] = sum_e wts[b][e] * sum_h x[b][h] * expert_w[e][h][d]
// wts nonzero only for top-2 experts per token -> grouped GEMV per expert.

constexpr int HD = 4096;   // hidden dim
constexpr int NE = 8;      // experts
constexpr int NB = 32;     // tokens
constexpr int TSLOT = 16;  // token slots per group (2 groups cover 32)
constexpr int NH = 16;     // h segments
constexpr int HSEG = HD / NH;    // 256
constexpr int ND = 4;      // d chunks
constexpr int DCHUNK = HD / ND;  // 1024

// ---------------- routing: logits + top-2 -> per-expert token lists -------
__global__ __launch_bounds__(256) void route_kernel(
    const float* __restrict__ x, const float* __restrict__ gw,
    int* __restrict__ cnt, int* __restrict__ toks, float* __restrict__ wts)
{
    const int tid = threadIdx.x;
    const int b = tid >> 3, e = tid & 7;   // 32 tokens x 8 experts = 256 threads
    const float4* x4 = (const float4*)(x + (size_t)b * HD);
    float acc = 0.f;
    for (int h4 = 0; h4 < HD / 4; ++h4) {
        float4 xv = x4[h4];
        int h = h4 * 4;
        acc += xv.x * gw[(h + 0) * NE + e];
        acc += xv.y * gw[(h + 1) * NE + e];
        acc += xv.z * gw[(h + 2) * NE + e];
        acc += xv.w * gw[(h + 3) * NE + e];
    }
    __shared__ float slog[NB][NE];
    slog[b][e] = acc;
    __syncthreads();
    if (tid == 0) {
        int c[NE];
        #pragma unroll
        for (int i = 0; i < NE; ++i) c[i] = 0;
        for (int bb = 0; bb < NB; ++bb) {
            float w0 = -3.4e38f; int e0 = 0;
            #pragma unroll
            for (int i = 0; i < NE; ++i) { float v = slog[bb][i]; if (v > w0) { w0 = v; e0 = i; } }
            float w1 = -3.4e38f; int e1 = 0;
            #pragma unroll
            for (int i = 0; i < NE; ++i) { if (i == e0) continue; float v = slog[bb][i]; if (v > w1) { w1 = v; e1 = i; } }
            // softmax weight of top-1: 1 / (1 + exp(w1 - w0)); top-2 gets 1-pre
            float pre = 1.0f / (1.0f + expf(w1 - w0));
            int s0 = c[e0]++; toks[e0 * NB + s0] = bb; wts[e0 * NB + s0] = pre;
            int s1 = c[e1]++; toks[e1 * NB + s1] = bb; wts[e1 * NB + s1] = 1.0f - pre;
        }
        #pragma unroll
        for (int i = 0; i < NE; ++i) cnt[i] = c[i];
    }
}

// ---------------- grouped GEMV over experts -------------------------------
// grid: (hseg, dchunk, e*2+g). Each block: W[e][h0:h0+256][d0:d0+1024] once,
// <=16 tokens' x rows (pre-scaled by combine weight) staged in LDS.
__global__ __launch_bounds__(256) void moe_gemv_kernel(
    const float* __restrict__ x, const float* __restrict__ ew,
    const int* __restrict__ cnt, const int* __restrict__ toks,
    const float* __restrict__ wts, float* __restrict__ out)
{
    const int hseg = blockIdx.x;
    const int dchunk = blockIdx.y;
    const int ez = blockIdx.z;
    const int e = ez >> 1, g = ez & 1;

    const int n = cnt[e];
    const int base = g * TSLOT;
    if (base >= n) return;                 // empty group
    int nt = n - base; if (nt > TSLOT) nt = TSLOT;

    __shared__ float xs[HSEG][TSLOT];      // [h][t], 16 KB
    __shared__ int   stok[TSLOT];
    __shared__ float swt[TSLOT];

    const int tid = threadIdx.x;
    if (tid < TSLOT) {
        if (tid < nt) {
            stok[tid] = toks[e * NB + base + tid];
            swt[tid]  = wts[e * NB + base + tid];
        } else {
            stok[tid] = 0;
            swt[tid]  = 0.0f;              // dead slot contributes 0
        }
    }
    __syncthreads();

    const int h0 = hseg * HSEG;
    {
        // stage xs[h][t] = wt_t * x[tok_t][h0+h]; thread = (t, h-block)
        const int t = tid & 15;
        const int hb = tid >> 4;           // 0..15
        const int tok = stok[t];
        const float wt = swt[t];
        const float* xp = x + (size_t)tok * HD + h0;
        #pragma unroll
        for (int it = 0; it < 4; ++it) {
            int h = it * 64 + hb * 4;
            float4 xv = *(const float4*)(xp + h);
            xs[h + 0][t] = wt * xv.x;
            xs[h + 1][t] = wt * xv.y;
            xs[h + 2][t] = wt * xv.z;
            xs[h + 3][t] = wt * xv.w;
        }
    }
    __syncthreads();

    const int d0 = dchunk * DCHUNK + tid * 4;
    const float* wp = ew + (size_t)e * HD * HD + (size_t)h0 * HD + d0;

    float ax[TSLOT], ay[TSLOT], az[TSLOT], aw[TSLOT];
    #pragma unroll
    for (int t = 0; t < TSLOT; ++t) { ax[t] = 0.f; ay[t] = 0.f; az[t] = 0.f; aw[t] = 0.f; }

    #pragma unroll 2
    for (int h = 0; h < HSEG; ++h) {
        float4 wv = *(const float4*)wp;    // 16B/lane coalesced W read
        wp += HD;
        #pragma unroll
        for (int q = 0; q < 4; ++q) {
            float4 xv = ((const float4*)(&xs[h][0]))[q];  // broadcast b128
            const int t = q * 4;
            ax[t+0] += xv.x * wv.x; ay[t+0] += xv.x * wv.y; az[t+0] += xv.x * wv.z; aw[t+0] += xv.x * wv.w;
            ax[t+1] += xv.y * wv.x; ay[t+1] += xv.y * wv.y; az[t+1] += xv.y * wv.z; aw[t+1] += xv.y * wv.w;
            ax[t+2] += xv.z * wv.x; ay[t+2] += xv.z * wv.y; az[t+2] += xv.z * wv.z; aw[t+2] += xv.z * wv.w;
            ax[t+3] += xv.w * wv.x; ay[t+3] += xv.w * wv.y; az[t+3] += xv.w * wv.z; aw[t+3] += xv.w * wv.w;
        }
    }

    #pragma unroll
    for (int t = 0; t < TSLOT; ++t) {
        if (t < nt) {                      // uniform branch, skip dead slots
            float* o = out + (size_t)stok[t] * HD + d0;
            atomicAdd(o + 0, ax[t]);
            atomicAdd(o + 1, ay[t]);
            atomicAdd(o + 2, az[t]);
            atomicAdd(o + 3, aw[t]);
        }
    }
}

extern "C" void kernel_launch(void* const* d_in, const int* in_sizes, int n_in,
                              void* d_out, int out_size, void* d_ws, size_t ws_size,
                              hipStream_t stream) {
    const float* x  = (const float*)d_in[0];   // [1,1,32,4096]
    const float* gw = (const float*)d_in[1];   // [4096,8]
    const float* ew = (const float*)d_in[2];   // [8,4096,4096]
    float* out = (float*)d_out;                // [1,1,32,4096] fp32

    int*   cnt  = (int*)d_ws;                  // 8
    int*   toks = cnt + NE;                    // 8*32
    float* wtsp = (float*)(toks + NE * NB);    // 8*32

    hipMemsetAsync(d_out, 0, (size_t)out_size * sizeof(float), stream);
    route_kernel<<<1, 256, 0, stream>>>(x, gw, cnt, toks, wtsp);
    dim3 grid(NH, ND, NE * 2);
    moe_gemv_kernel<<<grid, 256, 0, stream>>>(x, ew, cnt, toks, wtsp, out);
}

// Round 2
// 202.126 us; speedup vs baseline: 1.5846x; 1.5846x over previous
//
#include <hip/hip_runtime.h>
#include <math.h>

// MoE top-2: S=1, B=32, H=4096, E=8.
// out[b][d] = sum_{e in top2(b)} wt[b][e] * sum_h x[b][h] * expert_w[e][h][d]
// Memory-bound: expert_w = 537 MB read once ~ 85 us @ 6.3 TB/s.

constexpr int HD = 4096;
constexpr int NE = 8;
constexpr int NB = 32;
constexpr int TSLOT = 16;          // token slots per group (2 groups)
constexpr int NH = 32;             // h segments
constexpr int HSEG = HD / NH;      // 128
constexpr int ND = 4;              // d chunks
constexpr int DCHUNK = HD / ND;    // 1024 floats

// ---- routing: 1 block per token: logits, top-2, zero out row --------------
__global__ __launch_bounds__(256) void route_kernel(
    const float* __restrict__ x, const float* __restrict__ gw,
    int* __restrict__ re0, int* __restrict__ re1, float* __restrict__ rpre,
    float* __restrict__ out)
{
    const int b = blockIdx.x;           // 0..31
    const int tid = threadIdx.x;
    __shared__ float xrow[HD];          // 16 KB

    const float4* xsrc = (const float4*)(x + (size_t)b * HD);
    float4* outr = (float4*)(out + (size_t)b * HD);
    const float4 z = make_float4(0.f, 0.f, 0.f, 0.f);
    #pragma unroll
    for (int i = 0; i < HD / 4 / 256; ++i) {   // 4 iters
        int idx = i * 256 + tid;
        ((float4*)xrow)[idx] = xsrc[idx];
        outr[idx] = z;                  // zero output row (replaces memset)
    }
    __syncthreads();

    // thread (e = tid&7, hg = tid>>3) sums h = hg + 32*i  (conflict-free LDS,
    // coalesced gw: lane addr = (hg*8+e) + 256*i)
    const int e = tid & 7, hg = tid >> 3;
    float acc = 0.f;
    #pragma unroll 8
    for (int i = 0; i < HD / 32; ++i) {
        int h = hg + 32 * i;
        acc += xrow[h] * gw[h * NE + e];
    }
    __shared__ float part[32][NE];
    part[hg][e] = acc;
    __syncthreads();
    if (tid < NE) {
        float s = 0.f;
        #pragma unroll
        for (int i = 0; i < 32; ++i) s += part[i][tid];
        part[0][tid] = s;               // own column only: no race
    }
    __syncthreads();
    if (tid == 0) {
        float w0 = -3.4e38f; int e0 = 0;
        #pragma unroll
        for (int i = 0; i < NE; ++i) { float v = part[0][i]; if (v > w0) { w0 = v; e0 = i; } }
        float w1 = -3.4e38f; int e1 = 0;
        #pragma unroll
        for (int i = 0; i < NE; ++i) { if (i == e0) continue; float v = part[0][i]; if (v > w1) { w1 = v; e1 = i; } }
        float pre = 1.0f / (1.0f + expf(w1 - w0));   // top-1 combine weight
        re0[b] = e0; re1[b] = e1; rpre[b] = pre;
    }
}

// ---- grouped GEMV: block = (hseg, dchunk, e*2+g) --------------------------
__global__ __launch_bounds__(256, 4) void moe_gemv_kernel(
    const float* __restrict__ x, const float* __restrict__ ew,
    const int* __restrict__ re0, const int* __restrict__ re1,
    const float* __restrict__ rpre, float* __restrict__ out)
{
    const int hseg = blockIdx.x;        // 32
    const int dchunk = blockIdx.y;      // 4
    const int ez = blockIdx.z;          // 16
    const int e = ez >> 1, g = ez & 1;
    const int tid = threadIdx.x;

    __shared__ int   stok[TSLOT];
    __shared__ float swt[TSLOT];
    __shared__ int   snt;

    if (tid == 0) {
        int c = 0, nt = 0;
        for (int b = 0; b < NB; ++b) {
            int r0 = re0[b]; int r1 = re1[b]; float p = rpre[b];
            float w = 0.f; int hit = 0;
            if (r0 == e)      { w = p;        hit = 1; }
            else if (r1 == e) { w = 1.f - p;  hit = 1; }
            if (hit) {
                int s = c - g * TSLOT;
                if (s >= 0 && s < TSLOT) { stok[s] = b; swt[s] = w; ++nt; }
                ++c;
            }
        }
        snt = nt;
        for (int s = nt; s < TSLOT; ++s) { stok[s] = 0; swt[s] = 0.f; }
    }
    __syncthreads();
    const int nt = snt;
    if (nt == 0) return;                // uniform (g=1 nearly always)

    __shared__ float xs[HSEG][TSLOT];   // 8 KB, pre-scaled x
    const int h0 = hseg * HSEG;
    {
        const int t = tid & 15, hb = tid >> 4;      // hb 0..15 -> 8 h each
        const int tok = stok[t]; const float wt = swt[t];
        const float* xp = x + (size_t)tok * HD + h0 + hb * 8;
        #pragma unroll
        for (int it = 0; it < 2; ++it) {
            float4 v = *(const float4*)(xp + it * 4);
            int h = hb * 8 + it * 4;
            xs[h + 0][t] = wt * v.x; xs[h + 1][t] = wt * v.y;
            xs[h + 2][t] = wt * v.z; xs[h + 3][t] = wt * v.w;
        }
    }
    __syncthreads();

    const int d0 = dchunk * DCHUNK + tid * 4;
    const float* wp = ew + (size_t)e * HD * HD + (size_t)h0 * HD + d0;

    float4 acc[TSLOT];                  // 64 VGPRs
    #pragma unroll
    for (int t = 0; t < TSLOT; ++t) acc[t] = make_float4(0.f, 0.f, 0.f, 0.f);

    auto compute = [&](int h, const float4& wv) {
        #pragma unroll
        for (int q = 0; q < 4; ++q) {
            float4 xv = ((const float4*)(&xs[h][0]))[q];   // broadcast b128
            acc[q*4+0].x += xv.x * wv.x; acc[q*4+0].y += xv.x * wv.y;
            acc[q*4+0].z += xv.x * wv.z; acc[q*4+0].w += xv.x * wv.w;
            acc[q*4+1].x += xv.y * wv.x; acc[q*4+1].y += xv.y * wv.y;
            acc[q*4+1].z += xv.y * wv.z; acc[q*4+1].w += xv.y * wv.w;
            acc[q*4+2].x += xv.z * wv.x; acc[q*4+2].y += xv.z * wv.y;
            acc[q*4+2].z += xv.z * wv.z; acc[q*4+2].w += xv.z * wv.w;
            acc[q*4+3].x += xv.w * wv.x; acc[q*4+3].y += xv.w * wv.y;
            acc[q*4+3].z += xv.w * wv.z; acc[q*4+3].w += xv.w * wv.w;
        }
    };

    // 2-row software prefetch: next rows' loads in flight during FMAs
    float4 wv0 = *(const float4*)wp;
    float4 wv1 = *(const float4*)(wp + HD);
    wp += 2 * HD;
    for (int h = 0; h < HSEG - 2; h += 2) {
        float4 n0 = *(const float4*)wp;
        float4 n1 = *(const float4*)(wp + HD);
        wp += 2 * HD;
        compute(h, wv0);
        compute(h + 1, wv1);
        wv0 = n0; wv1 = n1;
    }
    compute(HSEG - 2, wv0);
    compute(HSEG - 1, wv1);

    #pragma unroll
    for (int t = 0; t < TSLOT; ++t) {
        if (t < nt) {
            float* o = out + (size_t)stok[t] * HD + d0;
            atomicAdd(o + 0, acc[t].x); atomicAdd(o + 1, acc[t].y);
            atomicAdd(o + 2, acc[t].z); atomicAdd(o + 3, acc[t].w);
        }
    }
}

extern "C" void kernel_launch(void* const* d_in, const int* in_sizes, int n_in,
                              void* d_out, int out_size, void* d_ws, size_t ws_size,
                              hipStream_t stream) {
    const float* x  = (const float*)d_in[0];   // [1,1,32,4096]
    const float* gw = (const float*)d_in[1];   // [4096,8]
    const float* ew = (const float*)d_in[2];   // [8,4096,4096]
    float* out = (float*)d_out;                // [1,1,32,4096] fp32

    int*   re0  = (int*)d_ws;                  // [32]
    int*   re1  = re0 + NB;                    // [32]
    float* rpre = (float*)(re1 + NB);          // [32]

    route_kernel<<<NB, 256, 0, stream>>>(x, gw, re0, re1, rpre, out);
    dim3 grid(NH, ND, NE * 2);
    moe_gemv_kernel<<<grid, 256, 0, stream>>>(x, ew, re0, re1, rpre, out);
}

// Round 3
// 128.019 us; speedup vs baseline: 2.5019x; 1.5789x over previous
//
#include <hip/hip_runtime.h>
#include <math.h>

// MoE top-2: S=1, B=32, H=4096, E=8.
// out[b][d] = sum_{e in top2(b)} wt[b][e] * sum_h x[b][h] * expert_w[e][h][d]
// Memory-bound: expert_w = 537 MB read once ~ 85 us @ 6.3 TB/s.
// R3: atomics -> partial buffer + reduce (64 same-address RMWs per dword
//     suspected as the R2 gap; partial tensor is fully overwritten each call).

constexpr int HD = 4096;
constexpr int NE = 8;
constexpr int NB = 32;
constexpr int TSLOT = 16;          // token slots per group (2 groups cover 32)
constexpr int NH = 32;             // h segments
constexpr int HSEG = HD / NH;      // 128
constexpr int ND = 4;              // d chunks
constexpr int DCHUNK = HD / ND;    // 1024 floats
constexpr int NPART = 2 * NH;      // 64 partial planes per token

// ---- routing: 1 block per token: logits -> top-2 -------------------------
__global__ __launch_bounds__(256) void route_kernel(
    const float* __restrict__ x, const float* __restrict__ gw,
    int* __restrict__ re0, int* __restrict__ re1, float* __restrict__ rpre)
{
    const int b = blockIdx.x;           // 0..31
    const int tid = threadIdx.x;
    __shared__ float xrow[HD];          // 16 KB

    const float4* xsrc = (const float4*)(x + (size_t)b * HD);
    #pragma unroll
    for (int i = 0; i < HD / 4 / 256; ++i) {   // 4 iters
        int idx = i * 256 + tid;
        ((float4*)xrow)[idx] = xsrc[idx];
    }
    __syncthreads();

    // thread (e = tid&7, hg = tid>>3) sums h = hg + 32*i  (conflict-free LDS,
    // coalesced gw reads)
    const int e = tid & 7, hg = tid >> 3;
    float acc = 0.f;
    #pragma unroll 8
    for (int i = 0; i < HD / 32; ++i) {
        int h = hg + 32 * i;
        acc += xrow[h] * gw[h * NE + e];
    }
    __shared__ float part[32][NE];
    part[hg][e] = acc;
    __syncthreads();
    if (tid < NE) {
        float s = 0.f;
        #pragma unroll
        for (int i = 0; i < 32; ++i) s += part[i][tid];
        part[0][tid] = s;               // own column only: no race
    }
    __syncthreads();
    if (tid == 0) {
        float w0 = -3.4e38f; int e0 = 0;
        #pragma unroll
        for (int i = 0; i < NE; ++i) { float v = part[0][i]; if (v > w0) { w0 = v; e0 = i; } }
        float w1 = -3.4e38f; int e1 = 0;
        #pragma unroll
        for (int i = 0; i < NE; ++i) { if (i == e0) continue; float v = part[0][i]; if (v > w1) { w1 = v; e1 = i; } }
        float pre = 1.0f / (1.0f + expf(w1 - w0));   // top-1 combine weight
        re0[b] = e0; re1[b] = e1; rpre[b] = pre;
    }
}

// ---- grouped GEMV: block = (hseg, dchunk, e*2+g); plain stores to part ---
__global__ __launch_bounds__(256, 4) void moe_gemv_kernel(
    const float* __restrict__ x, const float* __restrict__ ew,
    const int* __restrict__ re0, const int* __restrict__ re1,
    const float* __restrict__ rpre, float* __restrict__ part)
{
    const int hseg = blockIdx.x;        // 32
    const int dchunk = blockIdx.y;      // 4
    const int ez = blockIdx.z;          // 16
    const int e = ez >> 1, g = ez & 1;
    const int tid = threadIdx.x;

    __shared__ int   stok[TSLOT];
    __shared__ int   sslt[TSLOT];       // 0 if e is token's top-1, else 1
    __shared__ float swt[TSLOT];
    __shared__ int   snt;

    if (tid == 0) {
        int c = 0, nt = 0;
        for (int b = 0; b < NB; ++b) {
            int r0 = re0[b]; int r1 = re1[b]; float p = rpre[b];
            float w = 0.f; int hit = 0, sl = 0;
            if (r0 == e)      { w = p;        hit = 1; sl = 0; }
            else if (r1 == e) { w = 1.f - p;  hit = 1; sl = 1; }
            if (hit) {
                int s = c - g * TSLOT;
                if (s >= 0 && s < TSLOT) { stok[s] = b; swt[s] = w; sslt[s] = sl; ++nt; }
                ++c;
            }
        }
        snt = nt;
        for (int s = nt; s < TSLOT; ++s) { stok[s] = 0; swt[s] = 0.f; sslt[s] = 0; }
    }
    __syncthreads();
    const int nt = snt;
    if (nt == 0) return;                // uniform (g=1 nearly always)

    __shared__ float xs[HSEG][TSLOT];   // 8 KB, pre-scaled x
    const int h0 = hseg * HSEG;
    {
        const int t = tid & 15, hb = tid >> 4;      // hb 0..15 -> 8 h each
        const int tok = stok[t]; const float wt = swt[t];
        const float* xp = x + (size_t)tok * HD + h0 + hb * 8;
        #pragma unroll
        for (int it = 0; it < 2; ++it) {
            float4 v = *(const float4*)(xp + it * 4);
            int h = hb * 8 + it * 4;
            xs[h + 0][t] = wt * v.x; xs[h + 1][t] = wt * v.y;
            xs[h + 2][t] = wt * v.z; xs[h + 3][t] = wt * v.w;
        }
    }
    __syncthreads();

    const int d0 = dchunk * DCHUNK + tid * 4;
    const float* wp = ew + (size_t)e * HD * HD + (size_t)h0 * HD + d0;

    float4 acc[TSLOT];                  // 64 VGPRs
    #pragma unroll
    for (int t = 0; t < TSLOT; ++t) acc[t] = make_float4(0.f, 0.f, 0.f, 0.f);

    auto compute = [&](int h, const float4& wv) {
        #pragma unroll
        for (int q = 0; q < 4; ++q) {
            float4 xv = ((const float4*)(&xs[h][0]))[q];   // broadcast b128
            acc[q*4+0].x += xv.x * wv.x; acc[q*4+0].y += xv.x * wv.y;
            acc[q*4+0].z += xv.x * wv.z; acc[q*4+0].w += xv.x * wv.w;
            acc[q*4+1].x += xv.y * wv.x; acc[q*4+1].y += xv.y * wv.y;
            acc[q*4+1].z += xv.y * wv.z; acc[q*4+1].w += xv.y * wv.w;
            acc[q*4+2].x += xv.z * wv.x; acc[q*4+2].y += xv.z * wv.y;
            acc[q*4+2].z += xv.z * wv.z; acc[q*4+2].w += xv.z * wv.w;
            acc[q*4+3].x += xv.w * wv.x; acc[q*4+3].y += xv.w * wv.y;
            acc[q*4+3].z += xv.w * wv.z; acc[q*4+3].w += xv.w * wv.w;
        }
    };

    // 2-row software prefetch: next rows' loads in flight during FMAs
    float4 wv0 = *(const float4*)wp;
    float4 wv1 = *(const float4*)(wp + HD);
    wp += 2 * HD;
    for (int h = 0; h < HSEG - 2; h += 2) {
        float4 n0 = *(const float4*)wp;
        float4 n1 = *(const float4*)(wp + HD);
        wp += 2 * HD;
        compute(h, wv0);
        compute(h + 1, wv1);
        wv0 = n0; wv1 = n1;
    }
    compute(HSEG - 2, wv0);
    compute(HSEG - 1, wv1);

    // plain coalesced stores to partial planes (no atomics)
    #pragma unroll
    for (int t = 0; t < TSLOT; ++t) {
        if (t < nt) {
            float* p = part + ((size_t)(sslt[t] * NH + hseg) * NB + stok[t]) * HD + d0;
            *(float4*)p = acc[t];
        }
    }
}

// ---- reduce: out[b][d] = sum over 64 partial planes ----------------------
__global__ __launch_bounds__(256) void reduce_kernel(
    const float* __restrict__ part, float* __restrict__ out)
{
    const int idx = blockIdx.x * 256 + threadIdx.x;    // float4 index, 32768
    const float4* p4 = (const float4*)part;
    constexpr int PSTRIDE = NB * HD / 4;               // float4s per plane
    float4 s = make_float4(0.f, 0.f, 0.f, 0.f);
    #pragma unroll 8
    for (int j = 0; j < NPART; ++j) {
        float4 v = p4[(size_t)j * PSTRIDE + idx];
        s.x += v.x; s.y += v.y; s.z += v.z; s.w += v.w;
    }
    ((float4*)out)[idx] = s;
}

extern "C" void kernel_launch(void* const* d_in, const int* in_sizes, int n_in,
                              void* d_out, int out_size, void* d_ws, size_t ws_size,
                              hipStream_t stream) {
    const float* x  = (const float*)d_in[0];   // [1,1,32,4096]
    const float* gw = (const float*)d_in[1];   // [4096,8]
    const float* ew = (const float*)d_in[2];   // [8,4096,4096]
    float* out = (float*)d_out;                // [1,1,32,4096] fp32

    int*   re0  = (int*)d_ws;                  // [32]
    int*   re1  = re0 + NB;                    // [32]
    float* rpre = (float*)(re1 + NB);          // [32]
    float* partb = (float*)((char*)d_ws + 512);            // 64*32*4096 f32 = 32 MB
    // (re0/re1/rpre occupy the first 384 B; partial planes start at +512)

    route_kernel<<<NB, 256, 0, stream>>>(x, gw, re0, re1, rpre);
    dim3 grid(NH, ND, NE * 2);
    moe_gemv_kernel<<<grid, 256, 0, stream>>>(x, ew, re0, re1, rpre, partb);
    reduce_kernel<<<NB * HD / 4 / 256, 256, 0, stream>>>(partb, out);
}

// Round 4
// 124.968 us; speedup vs baseline: 2.5630x; 1.0244x over previous
//
#include <hip/hip_runtime.h>
#include <math.h>

// MoE top-2: S=1, B=32, H=4096, E=8.
// out[b][d] = sum_{e in top2(b)} wt[b][e] * sum_h x[b][h] * expert_w[e][h][d]
// Memory-bound: expert_w = 537 MB read once ~ 85 us @ 6.3 TB/s.
// R4: remove dead g=1 blocks (they halved live occupancy) -> one block per
//     (hseg, dchunk, expert), all tokens of the expert in passes of 16.

constexpr int HD = 4096;
constexpr int NE = 8;
constexpr int NB = 32;
constexpr int TSLOT = 16;          // token slots per pass
constexpr int MAXTOK = 32;         // an expert can serve at most all 32 tokens
constexpr int NH = 32;             // h segments
constexpr int HSEG = HD / NH;      // 128
constexpr int ND = 4;              // d chunks
constexpr int DCHUNK = HD / ND;    // 1024 floats
constexpr int NPART = 2 * NH;      // 64 partial planes per token

// ---- routing: 1 block per token: logits -> top-2 -------------------------
__global__ __launch_bounds__(256) void route_kernel(
    const float* __restrict__ x, const float* __restrict__ gw,
    int* __restrict__ re0, int* __restrict__ re1, float* __restrict__ rpre)
{
    const int b = blockIdx.x;           // 0..31
    const int tid = threadIdx.x;
    __shared__ float xrow[HD];          // 16 KB

    const float4* xsrc = (const float4*)(x + (size_t)b * HD);
    #pragma unroll
    for (int i = 0; i < HD / 4 / 256; ++i) {   // 4 iters
        int idx = i * 256 + tid;
        ((float4*)xrow)[idx] = xsrc[idx];
    }
    __syncthreads();

    const int e = tid & 7, hg = tid >> 3;
    float acc = 0.f;
    #pragma unroll 8
    for (int i = 0; i < HD / 32; ++i) {
        int h = hg + 32 * i;
        acc += xrow[h] * gw[h * NE + e];
    }
    __shared__ float part[32][NE];
    part[hg][e] = acc;
    __syncthreads();
    if (tid < NE) {
        float s = 0.f;
        #pragma unroll
        for (int i = 0; i < 32; ++i) s += part[i][tid];
        part[0][tid] = s;               // own column only: no race
    }
    __syncthreads();
    if (tid == 0) {
        float w0 = -3.4e38f; int e0 = 0;
        #pragma unroll
        for (int i = 0; i < NE; ++i) { float v = part[0][i]; if (v > w0) { w0 = v; e0 = i; } }
        float w1 = -3.4e38f; int e1 = 0;
        #pragma unroll
        for (int i = 0; i < NE; ++i) { if (i == e0) continue; float v = part[0][i]; if (v > w1) { w1 = v; e1 = i; } }
        float pre = 1.0f / (1.0f + expf(w1 - w0));   // top-1 combine weight
        re0[b] = e0; re1[b] = e1; rpre[b] = pre;
    }
}

// ---- grouped GEMV: block = (hseg, dchunk, e); all tokens of e ------------
__global__ __launch_bounds__(256, 4) void moe_gemv_kernel(
    const float* __restrict__ x, const float* __restrict__ ew,
    const int* __restrict__ re0, const int* __restrict__ re1,
    const float* __restrict__ rpre, float* __restrict__ part)
{
    const int hseg = blockIdx.x;        // 32
    const int dchunk = blockIdx.y;      // 4
    const int e = blockIdx.z;           // 8
    const int tid = threadIdx.x;

    __shared__ int   stok[MAXTOK];
    __shared__ int   sslt[MAXTOK];      // 0 if e is token's top-1, else 1
    __shared__ float swt[MAXTOK];
    __shared__ int   snt;

    if (tid == 0) {
        int c = 0;
        for (int b = 0; b < NB; ++b) {
            int r0 = re0[b]; int r1 = re1[b]; float p = rpre[b];
            if (r0 == e)      { stok[c] = b; swt[c] = p;       sslt[c] = 0; ++c; }
            else if (r1 == e) { stok[c] = b; swt[c] = 1.f - p; sslt[c] = 1; ++c; }
        }
        snt = c;
        int cp = (c + TSLOT - 1) & ~(TSLOT - 1);
        for (int s = c; s < cp; ++s) { stok[s] = 0; swt[s] = 0.f; sslt[s] = 0; }
    }
    __syncthreads();
    const int nt = snt;
    if (nt == 0) return;                // ~never (P < 0.2%)
    const int npass = (nt + TSLOT - 1) / TSLOT;   // block-uniform

    __shared__ float xs[HSEG][TSLOT];   // 8 KB, pre-scaled x
    const int h0 = hseg * HSEG;
    const int d0 = dchunk * DCHUNK + tid * 4;

    for (int p = 0; p < npass; ++p) {
        __syncthreads();                // protect xs from previous pass
        {
            const int t = tid & 15, hb = tid >> 4;  // hb 0..15 -> 8 h each
            const int s = p * TSLOT + t;
            const int tok = stok[s]; const float wt = swt[s];
            const float* xp = x + (size_t)tok * HD + h0 + hb * 8;
            #pragma unroll
            for (int it = 0; it < 2; ++it) {
                float4 v = *(const float4*)(xp + it * 4);
                int h = hb * 8 + it * 4;
                xs[h + 0][t] = wt * v.x; xs[h + 1][t] = wt * v.y;
                xs[h + 2][t] = wt * v.z; xs[h + 3][t] = wt * v.w;
            }
        }
        __syncthreads();

        const float* wp = ew + (size_t)e * HD * HD + (size_t)h0 * HD + d0;

        float4 acc[TSLOT];              // 64 VGPRs
        #pragma unroll
        for (int t = 0; t < TSLOT; ++t) acc[t] = make_float4(0.f, 0.f, 0.f, 0.f);

        auto compute = [&](int h, const float4& wv) {
            #pragma unroll
            for (int q = 0; q < 4; ++q) {
                float4 xv = ((const float4*)(&xs[h][0]))[q];   // broadcast b128
                acc[q*4+0].x += xv.x * wv.x; acc[q*4+0].y += xv.x * wv.y;
                acc[q*4+0].z += xv.x * wv.z; acc[q*4+0].w += xv.x * wv.w;
                acc[q*4+1].x += xv.y * wv.x; acc[q*4+1].y += xv.y * wv.y;
                acc[q*4+1].z += xv.y * wv.z; acc[q*4+1].w += xv.y * wv.w;
                acc[q*4+2].x += xv.z * wv.x; acc[q*4+2].y += xv.z * wv.y;
                acc[q*4+2].z += xv.z * wv.z; acc[q*4+2].w += xv.z * wv.w;
                acc[q*4+3].x += xv.w * wv.x; acc[q*4+3].y += xv.w * wv.y;
                acc[q*4+3].z += xv.w * wv.z; acc[q*4+3].w += xv.w * wv.w;
            }
        };

        // 2-row software prefetch
        float4 wv0 = *(const float4*)wp;
        float4 wv1 = *(const float4*)(wp + HD);
        wp += 2 * HD;
        for (int h = 0; h < HSEG - 2; h += 2) {
            float4 n0 = *(const float4*)wp;
            float4 n1 = *(const float4*)(wp + HD);
            wp += 2 * HD;
            compute(h, wv0);
            compute(h + 1, wv1);
            wv0 = n0; wv1 = n1;
        }
        compute(HSEG - 2, wv0);
        compute(HSEG - 1, wv1);

        // plain coalesced stores to partial planes (no atomics)
        #pragma unroll
        for (int t = 0; t < TSLOT; ++t) {
            const int s = p * TSLOT + t;
            if (s < nt) {
                float* pp = part + ((size_t)(sslt[s] * NH + hseg) * NB + stok[s]) * HD + d0;
                *(float4*)pp = acc[t];
            }
        }
    }
}

// ---- reduce: out[b][d] = sum over 64 partial planes ----------------------
__global__ __launch_bounds__(256) void reduce_kernel(
    const float* __restrict__ part, float* __restrict__ out)
{
    const int idx = blockIdx.x * 256 + threadIdx.x;    // float4 index, 32768
    const float4* p4 = (const float4*)part;
    constexpr int PSTRIDE = NB * HD / 4;               // float4s per plane
    float4 s = make_float4(0.f, 0.f, 0.f, 0.f);
    #pragma unroll 8
    for (int j = 0; j < NPART; ++j) {
        float4 v = p4[(size_t)j * PSTRIDE + idx];
        s.x += v.x; s.y += v.y; s.z += v.z; s.w += v.w;
    }
    ((float4*)out)[idx] = s;
}

extern "C" void kernel_launch(void* const* d_in, const int* in_sizes, int n_in,
                              void* d_out, int out_size, void* d_ws, size_t ws_size,
                              hipStream_t stream) {
    const float* x  = (const float*)d_in[0];   // [1,1,32,4096]
    const float* gw = (const float*)d_in[1];   // [4096,8]
    const float* ew = (const float*)d_in[2];   // [8,4096,4096]
    float* out = (float*)d_out;                // [1,1,32,4096] fp32

    int*   re0  = (int*)d_ws;                  // [32]
    int*   re1  = re0 + NB;                    // [32]
    float* rpre = (float*)(re1 + NB);          // [32]
    float* partb = (float*)((char*)d_ws + 512);            // 64*32*4096 f32 = 32 MB

    route_kernel<<<NB, 256, 0, stream>>>(x, gw, re0, re1, rpre);
    dim3 grid(NH, ND, NE);
    moe_gemv_kernel<<<grid, 256, 0, stream>>>(x, ew, re0, re1, rpre, partb);
    reduce_kernel<<<NB * HD / 4 / 256, 256, 0, stream>>>(partb, out);
}